// Round 5
// baseline (685.340 us; speedup 1.0000x reference)
//
#include <hip/hip_runtime.h>

#define CB 64
#define CN 4096
#define CD 256
#define CS 8
#define CH 512

typedef __bf16 bf16_t;
typedef bf16_t bf16x8 __attribute__((ext_vector_type(8)));
typedef float f32x4 __attribute__((ext_vector_type(4)));
typedef unsigned long long u64;
typedef u64 u64x2 __attribute__((ext_vector_type(2)));

__device__ __forceinline__ unsigned short f2bf(float f){
  unsigned int u = __builtin_bit_cast(unsigned int, f);
  u += 0x7FFFu + ((u >> 16) & 1u);
  return (unsigned short)(u >> 16);
}

__device__ __forceinline__ f32x4 mfma16(bf16x8 a, bf16x8 b, f32x4 c){
  return __builtin_amdgcn_mfma_f32_16x16x32_bf16(a, b, c, 0, 0, 0);
}

__device__ __forceinline__ void gl_lds16(const void* g, void* l){
  __builtin_amdgcn_global_load_lds(
      (const __attribute__((address_space(1))) unsigned int*)g,
      (__attribute__((address_space(3))) unsigned int*)l, 16, 0, 0);
}

// ---------------- LN over inputs -> x (bf16, row-major) ----------------
__global__ __launch_bounds__(256) void k_ln(const float* __restrict__ in,
    const float* __restrict__ gw, const float* __restrict__ gb,
    unsigned short* __restrict__ x){
  int blk = blockIdx.x;            // 4096 = 64 b * 64 ntiles
  int b = blk >> 6, nt = blk & 63;
  int wv = threadIdx.x >> 6, l = threadIdx.x & 63;
  const float* base = in + ((size_t)b*CN + (size_t)nt*64) * CD;
  unsigned short* xb = x + ((size_t)b*CN + (size_t)nt*64) * CD;
  float4 w4 = *(const float4*)(gw + 4*l);
  float4 b4 = *(const float4*)(gb + 4*l);
  for(int i = 0; i < 16; i++){
    int r = wv*16 + i;
    float4 v = *(const float4*)(base + (size_t)r*CD + 4*l);
    float s1 = v.x + v.y + v.z + v.w;
    float s2 = v.x*v.x + v.y*v.y + v.z*v.z + v.w*v.w;
    #pragma unroll
    for(int m = 1; m < 64; m <<= 1){ s1 += __shfl_xor(s1, m); s2 += __shfl_xor(s2, m); }
    float mean = s1 * (1.0f/CD);
    float var  = fmaxf(s2 * (1.0f/CD) - mean*mean, 0.0f);
    float rstd = rsqrtf(var + 1e-5f);
    float y0 = (v.x - mean)*rstd*w4.x + b4.x;
    float y1 = (v.y - mean)*rstd*w4.y + b4.y;
    float y2 = (v.z - mean)*rstd*w4.z + b4.z;
    float y3 = (v.w - mean)*rstd*w4.w + b4.w;
    uint2 p;
    p.x = (unsigned)f2bf(y0) | ((unsigned)f2bf(y1) << 16);
    p.y = (unsigned)f2bf(y2) | ((unsigned)f2bf(y3) << 16);
    *(uint2*)(xb + (size_t)r*CD + 4*l) = p;
  }
}

// ---------------- fused setup: M1T(bf16), bf16 weights [N][K], slots init ----------------
__global__ __launch_bounds__(256) void k_setup(
    const float* __restrict__ Wq, const float* __restrict__ Wk,
    const float* __restrict__ wih, const float* __restrict__ Wv,
    const float* __restrict__ whh, const float* __restrict__ w1,
    const float* __restrict__ w2, const float* __restrict__ noise,
    const float* __restrict__ mu, const float* __restrict__ lsig,
    unsigned short* __restrict__ M1T, unsigned short* __restrict__ Mih_bf,
    unsigned short* __restrict__ Whh_bf, unsigned short* __restrict__ w1_bf,
    unsigned short* __restrict__ w2_bf, float* __restrict__ slots){
  int bid = blockIdx.x, tid = threadIdx.x;
  if(bid < 256){                       // M1T[ep][e] = scale * sum_d Wq[d][e]*Wk[d][ep]
    int ep = bid, e = tid;
    float acc = 0.0f;
    for(int d = 0; d < 256; d++) acc = fmaf(Wq[(size_t)d*256 + e], Wk[(size_t)d*256 + ep], acc);
    M1T[(size_t)ep*256 + e] = f2bf(acc * 0.0625f);
  } else if(bid < 1024){               // Mih_bf[j][e] = sum_d wih[j][d]*Wv[d][e]  (768x256)
    int j = bid - 256, e = tid;
    float acc = 0.0f;
    for(int d = 0; d < 256; d++) acc = fmaf(wih[(size_t)j*256 + d], Wv[(size_t)d*256 + e], acc);
    Mih_bf[(size_t)j*256 + e] = f2bf(acc);
  } else if(bid < 1792){               // Whh_bf = bf16(whh), 768x256 row-major
    int idx = (bid - 1024)*256 + tid;
    Whh_bf[idx] = f2bf(whh[idx]);
  } else if(bid < 2304){               // w1_bf = bf16(w1), 512x256
    int idx = (bid - 1792)*256 + tid;
    w1_bf[idx] = f2bf(w1[idx]);
  } else if(bid < 2816){               // w2_bf = bf16(w2), 256x512
    int idx = (bid - 2304)*256 + tid;
    w2_bf[idx] = f2bf(w2[idx]);
  } else {                             // slots init, 131072 elems
    int idx = (bid - 2816)*256 + tid;
    int d = idx & 255;
    slots[idx] = mu[d] + __expf(lsig[d]) * noise[idx];
  }
}

// ---------------- fused attention: qt prologue -> double-buffered tiles -> Upart,dpart ----------
// X tile staged in SUBTILED layout: subtile S = (n>>2)*16 + (e>>4), 128 B each:
//   byte(n,e) = S*128 + (n&3)*32 + (e&15)*2
// Phase 1 reads A-fragments as b128 from subtiles; phase 2 uses ds_read_b64_tr_b16
// (per 16-lane group: addr = subtile_base + (lane&15)*8 delivers column lane&15, rows j=0..3).
// Double-buffered staging with counted vmcnt (never 0 mid-loop) + raw s_barrier.
__global__ __launch_bounds__(256) void k_attn(const unsigned short* __restrict__ x,
    const float* __restrict__ slots, const float* __restrict__ lsw,
    const float* __restrict__ lsb, const unsigned short* __restrict__ M1T,
    float* __restrict__ Upart, float* __restrict__ dpart){
  __shared__ unsigned short xb2[2][16384];   // 2 x 32 KB tile buffers
  __shared__ unsigned short pt[16*72];
  __shared__ float dred[4][8];
  int b = blockIdx.x >> 4, chunk = blockIdx.x & 15;   // 16 chunks -> 1024 blocks
  int tid = threadIdx.x;
  int wv = tid >> 6, l = tid & 63;
  int lm = l & 15, lg = l >> 4;

  // ---- prologue: qtile[16][264] = scale*LN(slots)@M1 in xb2[1]; sn in xb2[0] ----
  unsigned short* sn    = &xb2[0][0];
  unsigned short* qtile = &xb2[1][0];
  {
    float4 w4 = *(const float4*)(lsw + 4*l);
    float4 b4 = *(const float4*)(lsb + 4*l);
    for(int i = 0; i < 2; i++){
      int r = wv*2 + i;
      float4 v = *(const float4*)(slots + ((size_t)b*CS + r)*CD + 4*l);
      float s1 = v.x + v.y + v.z + v.w;
      float s2 = v.x*v.x + v.y*v.y + v.z*v.z + v.w*v.w;
      #pragma unroll
      for(int m = 1; m < 64; m <<= 1){ s1 += __shfl_xor(s1, m); s2 += __shfl_xor(s2, m); }
      float mean = s1 * (1.0f/CD);
      float var  = fmaxf(s2 * (1.0f/CD) - mean*mean, 0.0f);
      float rstd = rsqrtf(var + 1e-5f);
      float y0 = (v.x - mean)*rstd*w4.x + b4.x;
      float y1 = (v.y - mean)*rstd*w4.y + b4.y;
      float y2 = (v.z - mean)*rstd*w4.z + b4.z;
      float y3 = (v.w - mean)*rstd*w4.w + b4.w;
      uint2 p;
      p.x = (unsigned)f2bf(y0) | ((unsigned)f2bf(y1) << 16);
      p.y = (unsigned)f2bf(y2) | ((unsigned)f2bf(y3) << 16);
      *(uint2*)(&sn[r*264 + 4*l]) = p;
      uint2 zz; zz.x = 0u; zz.y = 0u;
      *(uint2*)(&sn[(r+8)*264 + 4*l]) = zz;
    }
    __syncthreads();
    bf16x8 af[8];
    #pragma unroll
    for(int k = 0; k < 8; k++) af[k] = *(const bf16x8*)(&sn[lm*264 + k*32 + lg*8]);
    #pragma unroll
    for(int ntile = 0; ntile < 4; ntile++){
      int ep = wv*64 + ntile*16 + lm;
      f32x4 acc = {0.f, 0.f, 0.f, 0.f};
      const unsigned short* mrow = M1T + (size_t)ep*CD;
      #pragma unroll
      for(int k = 0; k < 8; k++){
        bf16x8 bf = *(const bf16x8*)(mrow + k*32 + lg*8);
        acc = mfma16(af[k], bf, acc);
      }
      #pragma unroll
      for(int reg = 0; reg < 4; reg++)
        qtile[(lg*4 + reg)*264 + ep] = f2bf(acc[reg]);
    }
    __syncthreads();      // qtile visible; full drain (pre-loop, allowed)
  }
  bf16x8 qb[8];
  #pragma unroll
  for(int k = 0; k < 8; k++) qb[k] = *(const bf16x8*)(&qtile[lm*264 + k*32 + lg*8]);
  asm volatile("s_waitcnt lgkmcnt(0)" ::: "memory");
  __builtin_amdgcn_sched_barrier(0);
  __builtin_amdgcn_s_barrier();          // qb safe before DMA may overwrite xb2[1]

  f32x4 uacc[4];
  #pragma unroll
  for(int nt = 0; nt < 4; nt++){ f32x4 z = {0.f,0.f,0.f,0.f}; uacc[nt] = z; }
  float dacc = 0.0f;

  const unsigned short* xbatch = x + (size_t)b*CN*CD + (size_t)chunk*256*CD;

  // staging: per (wv,k2) one gl_lds16/lane -> 1 KB; lane l writes off = wv*8192 + k2*1024 + l*16 B
  //   inverse map: n = wv*16 + (k2>>1)*4 + ((l&7)>>1); e0 = ((k2&1)*8 + (l>>3))*16 + (l&1)*8
  #define STAGE(dstbuf, tptr) { \
    const unsigned short* xt_ = (tptr); \
    unsigned short* ld_ = (dstbuf) + wv*4096; \
    _Pragma("unroll") \
    for(int k2 = 0; k2 < 8; k2++){ \
      int n_  = wv*16 + (k2>>1)*4 + ((l&7)>>1); \
      int e0_ = ((k2&1)*8 + (l>>3))*16 + (l&1)*8; \
      gl_lds16(xt_ + (size_t)n_*CD + e0_, ld_ + k2*512); \
    } }

  STAGE(&xb2[0][0], xbatch);             // tile 0

  #pragma unroll
  for(int t = 0; t < 4; t++){
    if(t < 3) STAGE(&xb2[(t+1)&1][0], xbatch + (size_t)(t+1)*64*CD);
    if(t < 3) asm volatile("s_waitcnt vmcnt(8)" ::: "memory");
    else      asm volatile("s_waitcnt vmcnt(0)" ::: "memory");
    __builtin_amdgcn_sched_barrier(0);
    __builtin_amdgcn_s_barrier();        // tile t complete for all waves
    __builtin_amdgcn_sched_barrier(0);

    const unsigned short* xcur = &xb2[t&1][0];
    // phase 1: logits for this wave's 16 rows (subtiled A reads)
    f32x4 c4 = {0.f, 0.f, 0.f, 0.f};
    {
      int abase = wv*4096 + (lm>>2)*1024 + (lm&3)*16 + (lg>>1)*64 + (lg&1)*8;  // shorts
      #pragma unroll
      for(int k = 0; k < 8; k++){
        bf16x8 a = *(const bf16x8*)(xcur + abase + k*128);
        c4 = mfma16(a, qb[k], c4);
      }
    }
    // softmax over slots
    float pv[4];
    #pragma unroll
    for(int reg = 0; reg < 4; reg++){
      float v = (lm < 8) ? c4[reg] : -1e30f;
      float mx = v;
      #pragma unroll
      for(int m = 1; m < 16; m <<= 1) mx = fmaxf(mx, __shfl_xor(mx, m));
      float e = __expf(v - mx);
      float s = e;
      #pragma unroll
      for(int m = 1; m < 16; m <<= 1) s += __shfl_xor(s, m);
      float p = (lm < 8) ? (e/s + 1e-8f) : 0.0f;
      dacc += p;
      pv[reg] = p;
    }
    int rbase = wv*16 + lg*4;
    unsigned int p01 = (unsigned)f2bf(pv[0]) | ((unsigned)f2bf(pv[1]) << 16);
    unsigned int p23 = (unsigned)f2bf(pv[2]) | ((unsigned)f2bf(pv[3]) << 16);
    *(unsigned int*)(&pt[lm*72 + rbase])     = p01;
    *(unsigned int*)(&pt[lm*72 + rbase + 2]) = p23;
    asm volatile("s_waitcnt lgkmcnt(0)" ::: "memory");
    __builtin_amdgcn_sched_barrier(0);
    __builtin_amdgcn_s_barrier();        // pt visible to all waves
    __builtin_amdgcn_sched_barrier(0);

    // phase 2: U[s, e-slice] += P^T @ X via hardware transpose reads
    {
      bf16x8 aP0 = *(const bf16x8*)(&pt[lm*72 + lg*8]);
      bf16x8 aP1 = *(const bf16x8*)(&pt[lm*72 + 32 + lg*8]);
      // base addr: subtile (R1 = lg*2, C = wv*4+nt), column lane lm
      unsigned xoff = (unsigned)(size_t)xcur;
      unsigned bse = xoff + (unsigned)(lg*2*16*128 + wv*4*128 + lm*8);
      u64 t0[4], t1[4], t2[4], t3[4];
      #pragma unroll
      for(int nt = 0; nt < 4; nt++){
        unsigned a0 = bse + nt*128;
        asm volatile("ds_read_b64_tr_b16 %0, %4\n\t"
                     "ds_read_b64_tr_b16 %1, %4 offset:2048\n\t"
                     "ds_read_b64_tr_b16 %2, %4 offset:16384\n\t"
                     "ds_read_b64_tr_b16 %3, %4 offset:18432"
                     : "=v"(t0[nt]), "=v"(t1[nt]), "=v"(t2[nt]), "=v"(t3[nt])
                     : "v"(a0));
      }
      asm volatile("s_waitcnt lgkmcnt(0)" ::: "memory");
      __builtin_amdgcn_sched_barrier(0);
      #pragma unroll
      for(int nt = 0; nt < 4; nt++){
        u64x2 q0; q0[0] = t0[nt]; q0[1] = t1[nt];
        u64x2 q1; q1[0] = t2[nt]; q1[1] = t3[nt];
        uacc[nt] = mfma16(aP0, __builtin_bit_cast(bf16x8, q0), uacc[nt]);
        uacc[nt] = mfma16(aP1, __builtin_bit_cast(bf16x8, q1), uacc[nt]);
      }
    }
    __builtin_amdgcn_s_barrier();        // buf[t] reads done before its next overwrite
    __builtin_amdgcn_sched_barrier(0);
  }
  #undef STAGE

  // epilogue: plain stores of partials (no atomics)
  dacc += __shfl_xor(dacc, 16);
  dacc += __shfl_xor(dacc, 32);
  if(l < 8) dred[wv][l] = dacc;
  if(lg < 2){
    float* Ub = Upart + (((size_t)chunk*CB + b)*CS)*CD;
    #pragma unroll
    for(int nt = 0; nt < 4; nt++){
      #pragma unroll
      for(int reg = 0; reg < 4; reg++){
        int s = lg*4 + reg;
        Ub[(size_t)s*CD + wv*64 + nt*16 + lm] = uacc[nt][reg];
      }
    }
  }
  __syncthreads();
  if(tid < 8)
    dpart[((size_t)chunk*CB + b)*CS + tid] =
        dred[0][tid] + dred[1][tid] + dred[2][tid] + dred[3][tid];
}

// ---------------- fused slot update, 8-wave; reduces 16 U/den partials in staging ----------------
__global__ __launch_bounds__(512) void k_update(
    const float* __restrict__ Upart, const float* slots,
    const float* __restrict__ dpart,
    const unsigned short* __restrict__ Mih, const unsigned short* __restrict__ Whh,
    const unsigned short* __restrict__ w1b, const unsigned short* __restrict__ w2b,
    const float* __restrict__ bih, const float* __restrict__ bhh,
    const float* __restrict__ lmw, const float* __restrict__ lmb,
    const float* __restrict__ b1, const float* __restrict__ b2,
    float* out){
  __shared__ unsigned short A1[16*264];   // bf16 A-operand: U, then lnh
  __shared__ unsigned short SBf[16*264];  // bf16 slots
  __shared__ unsigned short A3[16*520];   // bf16 h1 (K=512)
  __shared__ float G1[8*777];             // gi raw
  __shared__ float G2[8*777];             // gh raw
  __shared__ float Hh[8*257];             // GRU output h (residual base)
  int b = blockIdx.x, tid = threadIdx.x;
  int l = tid & 63, lm = l & 15, lg = l >> 4;
  int wv = tid >> 6;

  // zero pad rows 8..15 of A-operands (keeps D rows 8..15 = 0)
  for(int i = tid; i < 8*264; i += 512){ A1[8*264 + i] = 0; SBf[8*264 + i] = 0; }
  for(int i = tid; i < 8*520; i += 512) A3[8*520 + i] = 0;
  // stage U (threads 0..255, summing 16 partials) and slots (threads 256..511)
  if(tid < 256){
    int r = tid >> 5, c = (tid & 31)*8;
    float s0=0.f,s1=0.f,s2=0.f,s3=0.f,s4=0.f,s5=0.f,s6=0.f,s7=0.f;
    #pragma unroll
    for(int ch = 0; ch < 16; ch++){
      const float* Up = Upart + (((size_t)ch*CB + b)*CS + r)*CD + c;
      float4 a0 = *(const float4*)Up;
      float4 a1 = *(const float4*)(Up + 4);
      s0 += a0.x; s1 += a0.y; s2 += a0.z; s3 += a0.w;
      s4 += a1.x; s5 += a1.y; s6 += a1.z; s7 += a1.w;
    }
    uint4 pk;
    pk.x = (unsigned)f2bf(s0) | ((unsigned)f2bf(s1) << 16);
    pk.y = (unsigned)f2bf(s2) | ((unsigned)f2bf(s3) << 16);
    pk.z = (unsigned)f2bf(s4) | ((unsigned)f2bf(s5) << 16);
    pk.w = (unsigned)f2bf(s6) | ((unsigned)f2bf(s7) << 16);
    *(uint4*)(&A1[r*264 + c]) = pk;
  } else {
    int t2 = tid & 255;
    int r = t2 >> 5, c = (t2 & 31)*8;
    const float* src = slots + ((size_t)b*CS + r)*CD + c;
    float4 a0 = *(const float4*)src, a1 = *(const float4*)(src + 4);
    uint4 pk;
    pk.x = (unsigned)f2bf(a0.x) | ((unsigned)f2bf(a0.y) << 16);
    pk.y = (unsigned)f2bf(a0.z) | ((unsigned)f2bf(a0.w) << 16);
    pk.z = (unsigned)f2bf(a1.x) | ((unsigned)f2bf(a1.y) << 16);
    pk.w = (unsigned)f2bf(a1.z) | ((unsigned)f2bf(a1.w) << 16);
    *(uint4*)(&SBf[r*264 + c]) = pk;
  }
  __syncthreads();

  // P1: gi = U@Mih^T (waves 0-3), gh = slots@Whh^T (waves 4-7); N=768, K=256 each.
  {
    const unsigned short* W = (wv < 4) ? Mih : Whh;
    const unsigned short* As = (wv < 4) ? A1 : SBf;
    float* G = (wv < 4) ? G1 : G2;
    int w4 = wv & 3;
    bf16x8 af[8];
    #pragma unroll
    for(int k = 0; k < 8; k++) af[k] = *(const bf16x8*)(&As[lm*264 + k*32 + lg*8]);
    const unsigned short* brow = W + ((size_t)(w4*192 + lm))*CD + lg*8;
    bf16x8 bv[8], bw[8];
    #pragma unroll
    for(int k = 0; k < 8; k++) bv[k] = *(const bf16x8*)(brow + k*32);
    for(int t = 0; t < 12; t++){
      if(t < 11){
        const unsigned short* bn = brow + (size_t)(t + 1)*16*CD;
        #pragma unroll
        for(int k = 0; k < 8; k++) bw[k] = *(const bf16x8*)(bn + k*32);
      }
      f32x4 acc = {0.f,0.f,0.f,0.f};
      #pragma unroll
      for(int k = 0; k < 8; k++) acc = mfma16(af[k], bv[k], acc);
      if(lg < 2){
        int cb = w4*192 + t*16 + lm;
        #pragma unroll
        for(int reg = 0; reg < 4; reg++) G[(lg*4 + reg)*777 + cb] = acc[reg];
      }
      #pragma unroll
      for(int k = 0; k < 8; k++) bv[k] = bw[k];
    }
  }
  __syncthreads();

  // P2: GRU gate activations + LN(mlp) -> A1 (bf16 lnh); one wave per slot row
  {
    int r = wv;
    float dsum = dpart[((size_t)(l & 15)*CB + b)*CS + r];
    #pragma unroll
    for(int m = 1; m < 16; m <<= 1) dsum += __shfl_xor(dsum, m);
    float invd = 1.0f / dsum;
    const float* srow = slots + ((size_t)b*CS + r)*CD;
    float hv[4]; float s1 = 0.f, s2 = 0.f;
    #pragma unroll
    for(int i = 0; i < 4; i++){
      int c = l + 64*i;
      float gr = G1[r*777 + c]*invd + bih[c] + G2[r*777 + c] + bhh[c];
      float gz = G1[r*777 + 256 + c]*invd + bih[256 + c] + G2[r*777 + 256 + c] + bhh[256 + c];
      float gn = G1[r*777 + 512 + c]*invd + bih[512 + c];
      float hn = G2[r*777 + 512 + c] + bhh[512 + c];
      float rr = 1.0f/(1.0f + __expf(-gr));
      float zz = 1.0f/(1.0f + __expf(-gz));
      float nn = tanhf(gn + rr*hn);
      float h = (1.0f - zz)*nn + zz*srow[c];
      hv[i] = h; Hh[r*257 + c] = h; s1 += h; s2 += h*h;
    }
    #pragma unroll
    for(int m = 1; m < 64; m <<= 1){ s1 += __shfl_xor(s1, m); s2 += __shfl_xor(s2, m); }
    float mean = s1 * (1.0f/CD);
    float var  = fmaxf(s2 * (1.0f/CD) - mean*mean, 0.0f);
    float rstd = rsqrtf(var + 1e-5f);
    #pragma unroll
    for(int i = 0; i < 4; i++){
      int c = l + 64*i;
      A1[r*264 + c] = f2bf((hv[i] - mean)*rstd*lmw[c] + lmb[c]);
    }
  }
  __syncthreads();

  // P3: h1 = relu(lnh@w1^T + b1) -> A3 bf16   (N=512, K=256; 4 col-tiles per wave)
  {
    bf16x8 af[8];
    #pragma unroll
    for(int k = 0; k < 8; k++) af[k] = *(const bf16x8*)(&A1[lm*264 + k*32 + lg*8]);
    const unsigned short* brow = w1b + ((size_t)(wv*64 + lm))*CD + lg*8;
    for(int t = 0; t < 4; t++){
      const unsigned short* bn = brow + (size_t)t*16*CD;
      f32x4 acc = {0.f,0.f,0.f,0.f};
      #pragma unroll
      for(int k = 0; k < 8; k++){
        bf16x8 bv = *(const bf16x8*)(bn + k*32);
        acc = mfma16(af[k], bv, acc);
      }
      if(lg < 2){
        int c = wv*64 + t*16 + lm;
        float bb = b1[c];
        #pragma unroll
        for(int reg = 0; reg < 4; reg++)
          A3[(lg*4 + reg)*520 + c] = f2bf(fmaxf(acc[reg] + bb, 0.0f));
      }
    }
  }
  __syncthreads();

  // P4: out = h1@w2^T + b2 + Hh   (N=256, K=512; 2 col-tiles per wave)
  {
    bf16x8 af[16];
    #pragma unroll
    for(int k = 0; k < 16; k++) af[k] = *(const bf16x8*)(&A3[lm*520 + k*32 + lg*8]);
    const unsigned short* brow = w2b + ((size_t)(wv*32 + lm))*CH + lg*8;
    for(int t = 0; t < 2; t++){
      const unsigned short* bn = brow + (size_t)t*16*CH;
      f32x4 acc = {0.f,0.f,0.f,0.f};
      #pragma unroll
      for(int k = 0; k < 16; k++){
        bf16x8 bv = *(const bf16x8*)(bn + k*32);
        acc = mfma16(af[k], bv, acc);
      }
      if(lg < 2){
        int c = wv*32 + t*16 + lm;
        float bb = b2[c];
        #pragma unroll
        for(int reg = 0; reg < 4; reg++){
          int row = lg*4 + reg;
          out[((size_t)b*CS + row)*CD + c] = acc[reg] + bb + Hh[row*257 + c];
        }
      }
    }
  }
}

extern "C" void kernel_launch(void* const* d_in, const int* in_sizes, int n_in,
                              void* d_out, int out_size, void* d_ws, size_t ws_size,
                              hipStream_t stream){
  const float* inputs = (const float*)d_in[0];
  const float* noise  = (const float*)d_in[1];
  const float* ln_in_w = (const float*)d_in[2];
  const float* ln_in_b = (const float*)d_in[3];
  const float* ln_sl_w = (const float*)d_in[4];
  const float* ln_sl_b = (const float*)d_in[5];
  const float* ln_ml_w = (const float*)d_in[6];
  const float* ln_ml_b = (const float*)d_in[7];
  const float* mu   = (const float*)d_in[8];
  const float* lsig = (const float*)d_in[9];
  const float* Wq  = (const float*)d_in[10];
  const float* Wk  = (const float*)d_in[11];
  const float* Wv  = (const float*)d_in[12];
  const float* wih = (const float*)d_in[13];
  const float* whh = (const float*)d_in[14];
  const float* bih = (const float*)d_in[15];
  const float* bhh = (const float*)d_in[16];
  const float* w1  = (const float*)d_in[17];
  const float* b1  = (const float*)d_in[18];
  const float* w2  = (const float*)d_in[19];
  const float* b2  = (const float*)d_in[20];

  char* ws = (char*)d_ws;
  size_t off = 0;
  unsigned short* x = (unsigned short*)(ws + off); off += (size_t)CB*CN*CD*2;
  float* slots = (float*)(ws + off); off += (size_t)CB*CS*CD*4;
  float* Upart = (float*)(ws + off); off += (size_t)16*CB*CS*CD*4;
  float* dpart = (float*)(ws + off); off += (size_t)16*CB*CS*4;
  unsigned short* M1T    = (unsigned short*)(ws + off); off += (size_t)CD*CD*2;
  unsigned short* Mih_bf = (unsigned short*)(ws + off); off += (size_t)768*CD*2;
  unsigned short* Whh_bf = (unsigned short*)(ws + off); off += (size_t)768*CD*2;
  unsigned short* w1_bf  = (unsigned short*)(ws + off); off += (size_t)CH*CD*2;
  unsigned short* w2_bf  = (unsigned short*)(ws + off); off += (size_t)CD*CH*2;

  k_ln<<<4096, 256, 0, stream>>>(inputs, ln_in_w, ln_in_b, x);
  k_setup<<<3328, 256, 0, stream>>>(Wq, Wk, wih, Wv, whh, w1, w2, noise, mu, lsig,
                                    M1T, Mih_bf, Whh_bf, w1_bf, w2_bf, slots);

  for(int it = 0; it < 3; it++){
    k_attn<<<1024, 256, 0, stream>>>(x, slots, ln_sl_w, ln_sl_b, M1T, Upart, dpart);
    float* dst = (it == 2) ? (float*)d_out : slots;
    k_update<<<64, 512, 0, stream>>>(Upart, slots, dpart,
        Mih_bf, Whh_bf, w1_bf, w2_bf,
        bih, bhh, ln_ml_w, ln_ml_b, b1, b2, dst);
  }
}

// Round 6
// 665.602 us; speedup vs baseline: 1.0297x; 1.0297x over previous
//
#include <hip/hip_runtime.h>

#define CB 64
#define CN 4096
#define CD 256
#define CS 8
#define CH 512

typedef __bf16 bf16_t;
typedef bf16_t bf16x8 __attribute__((ext_vector_type(8)));
typedef float f32x4 __attribute__((ext_vector_type(4)));

__device__ __forceinline__ unsigned short f2bf(float f){
  unsigned int u = __builtin_bit_cast(unsigned int, f);
  u += 0x7FFFu + ((u >> 16) & 1u);
  return (unsigned short)(u >> 16);
}

__device__ __forceinline__ f32x4 mfma16(bf16x8 a, bf16x8 b, f32x4 c){
  return __builtin_amdgcn_mfma_f32_16x16x32_bf16(a, b, c, 0, 0, 0);
}

__device__ __forceinline__ void gl_lds16(const void* g, void* l){
  __builtin_amdgcn_global_load_lds(
      (const __attribute__((address_space(1))) unsigned int*)g,
      (__attribute__((address_space(3))) unsigned int*)l, 16, 0, 0);
}

// ---------------- merged pre-pass: setup blocks (0..3327) + LN blocks (3328..7423) --------------
// Setup blocks first: latency-bound, hide under the BW-bound LN sweep; one less launch gap.
__global__ __launch_bounds__(256) void k_pre(
    const float* __restrict__ in, const float* __restrict__ gw,
    const float* __restrict__ gb, unsigned short* __restrict__ x,
    const float* __restrict__ Wq, const float* __restrict__ Wk,
    const float* __restrict__ wih, const float* __restrict__ Wv,
    const float* __restrict__ whh, const float* __restrict__ w1,
    const float* __restrict__ w2, const float* __restrict__ noise,
    const float* __restrict__ mu, const float* __restrict__ lsig,
    unsigned short* __restrict__ M1T, unsigned short* __restrict__ Mih_bf,
    unsigned short* __restrict__ Whh_bf, unsigned short* __restrict__ w1_bf,
    unsigned short* __restrict__ w2_bf, float* __restrict__ slots){
  int bid = blockIdx.x, tid = threadIdx.x;
  if(bid < 3328){
    // ---- setup ----
    if(bid < 256){                       // M1T[ep][e] = scale * sum_d Wq[d][e]*Wk[d][ep]
      int ep = bid, e = tid;
      float acc = 0.0f;
      for(int d = 0; d < 256; d++) acc = fmaf(Wq[(size_t)d*256 + e], Wk[(size_t)d*256 + ep], acc);
      M1T[(size_t)ep*256 + e] = f2bf(acc * 0.0625f);
    } else if(bid < 1024){               // Mih_bf[j][e] = sum_d wih[j][d]*Wv[d][e]  (768x256)
      int j = bid - 256, e = tid;
      float acc = 0.0f;
      for(int d = 0; d < 256; d++) acc = fmaf(wih[(size_t)j*256 + d], Wv[(size_t)d*256 + e], acc);
      Mih_bf[(size_t)j*256 + e] = f2bf(acc);
    } else if(bid < 1792){               // Whh_bf = bf16(whh), 768x256 row-major
      int idx = (bid - 1024)*256 + tid;
      Whh_bf[idx] = f2bf(whh[idx]);
    } else if(bid < 2304){               // w1_bf = bf16(w1), 512x256
      int idx = (bid - 1792)*256 + tid;
      w1_bf[idx] = f2bf(w1[idx]);
    } else if(bid < 2816){               // w2_bf = bf16(w2), 256x512
      int idx = (bid - 2304)*256 + tid;
      w2_bf[idx] = f2bf(w2[idx]);
    } else {                             // slots init, 131072 elems
      int idx = (bid - 2816)*256 + tid;
      int d = idx & 255;
      slots[idx] = mu[d] + __expf(lsig[d]) * noise[idx];
    }
    return;
  }
  // ---- LN over inputs -> x (bf16, row-major) ----
  int blk = bid - 3328;                  // 4096 = 64 b * 64 ntiles
  int b = blk >> 6, nt = blk & 63;
  int wv = tid >> 6, l = tid & 63;
  const float* base = in + ((size_t)b*CN + (size_t)nt*64) * CD;
  unsigned short* xb = x + ((size_t)b*CN + (size_t)nt*64) * CD;
  float4 w4 = *(const float4*)(gw + 4*l);
  float4 b4 = *(const float4*)(gb + 4*l);
  for(int i = 0; i < 16; i++){
    int r = wv*16 + i;
    float4 v = *(const float4*)(base + (size_t)r*CD + 4*l);
    float s1 = v.x + v.y + v.z + v.w;
    float s2 = v.x*v.x + v.y*v.y + v.z*v.z + v.w*v.w;
    #pragma unroll
    for(int m = 1; m < 64; m <<= 1){ s1 += __shfl_xor(s1, m); s2 += __shfl_xor(s2, m); }
    float mean = s1 * (1.0f/CD);
    float var  = fmaxf(s2 * (1.0f/CD) - mean*mean, 0.0f);
    float rstd = rsqrtf(var + 1e-5f);
    float y0 = (v.x - mean)*rstd*w4.x + b4.x;
    float y1 = (v.y - mean)*rstd*w4.y + b4.y;
    float y2 = (v.z - mean)*rstd*w4.z + b4.z;
    float y3 = (v.w - mean)*rstd*w4.w + b4.w;
    uint2 p;
    p.x = (unsigned)f2bf(y0) | ((unsigned)f2bf(y1) << 16);
    p.y = (unsigned)f2bf(y2) | ((unsigned)f2bf(y3) << 16);
    *(uint2*)(xb + (size_t)r*CD + 4*l) = p;
  }
}

// ---------------- qt = scale*LN(slots)@M1 (bf16, rows 8..15 zero); also zeros U,den ----------------
__global__ __launch_bounds__(256) void k_qt(const float* __restrict__ slots,
    const float* __restrict__ lw, const float* __restrict__ lb,
    const unsigned short* __restrict__ M1T, unsigned short* __restrict__ qt,
    float* __restrict__ U, float* __restrict__ den){
  __shared__ unsigned short sn[16*264];
  int b = blockIdx.x;
  int tid = threadIdx.x;
  float4 z4 = {0.f, 0.f, 0.f, 0.f};
  float* Ub = U + (size_t)b*CS*CD;
  *(float4*)(Ub + tid*8)     = z4;
  *(float4*)(Ub + tid*8 + 4) = z4;
  if(tid < CS) den[b*CS + tid] = 0.0f;

  int wv = tid >> 6, l = tid & 63;
  int lm = l & 15, lg = l >> 4;
  float4 w4 = *(const float4*)(lw + 4*l);
  float4 b4 = *(const float4*)(lb + 4*l);
  for(int i = 0; i < 2; i++){
    int r = wv*2 + i;
    float4 v = *(const float4*)(slots + ((size_t)b*CS + r)*CD + 4*l);
    float s1 = v.x + v.y + v.z + v.w;
    float s2 = v.x*v.x + v.y*v.y + v.z*v.z + v.w*v.w;
    #pragma unroll
    for(int m = 1; m < 64; m <<= 1){ s1 += __shfl_xor(s1, m); s2 += __shfl_xor(s2, m); }
    float mean = s1 * (1.0f/CD);
    float var  = fmaxf(s2 * (1.0f/CD) - mean*mean, 0.0f);
    float rstd = rsqrtf(var + 1e-5f);
    float y0 = (v.x - mean)*rstd*w4.x + b4.x;
    float y1 = (v.y - mean)*rstd*w4.y + b4.y;
    float y2 = (v.z - mean)*rstd*w4.z + b4.z;
    float y3 = (v.w - mean)*rstd*w4.w + b4.w;
    uint2 p;
    p.x = (unsigned)f2bf(y0) | ((unsigned)f2bf(y1) << 16);
    p.y = (unsigned)f2bf(y2) | ((unsigned)f2bf(y3) << 16);
    *(uint2*)(&sn[r*264 + 4*l]) = p;
    uint2 zz; zz.x = 0u; zz.y = 0u;
    *(uint2*)(&sn[(r+8)*264 + 4*l]) = zz;
  }
  __syncthreads();
  bf16x8 af[8];
  #pragma unroll
  for(int k = 0; k < 8; k++) af[k] = *(const bf16x8*)(&sn[lm*264 + k*32 + lg*8]);
  #pragma unroll
  for(int ntile = 0; ntile < 4; ntile++){
    int ep = wv*64 + ntile*16 + lm;
    f32x4 acc = {0.f, 0.f, 0.f, 0.f};
    const unsigned short* mrow = M1T + (size_t)ep*CD;
    #pragma unroll
    for(int k = 0; k < 8; k++){
      bf16x8 bf = *(const bf16x8*)(mrow + k*32 + lg*8);
      acc = mfma16(af[k], bf, acc);
    }
    #pragma unroll
    for(int reg = 0; reg < 4; reg++){
      int s = lg*4 + reg;
      qt[((size_t)b*16 + s)*CD + ep] = f2bf(acc[reg]);
    }
  }
}

// ---------------- fused attention pass: logits -> softmax+eps -> U,den ----------------
__global__ __launch_bounds__(256) void k_attn(const unsigned short* __restrict__ x,
    const unsigned short* __restrict__ qt, float* __restrict__ U, float* __restrict__ den){
  __shared__ unsigned short xt[64*256];
  __shared__ unsigned short pt[16*72];
  int b = blockIdx.x >> 4, chunk = blockIdx.x & 15;   // 16 chunks -> 1024 blocks
  int wv = threadIdx.x >> 6, l = threadIdx.x & 63;
  int lm = l & 15, lg = l >> 4;

  bf16x8 qb[8];
  const unsigned short* qrow = qt + ((size_t)b*16 + lm)*CD;
  #pragma unroll
  for(int k = 0; k < 8; k++) qb[k] = *(const bf16x8*)(qrow + k*32 + lg*8);

  f32x4 uacc[4];
  #pragma unroll
  for(int nt = 0; nt < 4; nt++){ f32x4 z = {0.f,0.f,0.f,0.f}; uacc[nt] = z; }
  float dacc = 0.0f;

  const unsigned short* xbatch = x + (size_t)b*CN*CD + (size_t)chunk*256*CD;

  for(int t = 0; t < 4; t++){
    const unsigned short* xtile = xbatch + (size_t)t*64*CD;
    __syncthreads();
    #pragma unroll
    for(int k2 = 0; k2 < 8; k2++){
      int r0 = wv*16 + k2*2;
      int row = r0 + (l >> 5);
      int c = l & 31;
      int f = (row ^ (row >> 3)) & 7;
      const unsigned short* g = xtile + (size_t)row*CD + (size_t)(c ^ f)*8;
      gl_lds16(g, &xt[r0*CD]);
    }
    __syncthreads();

    // phase 1: logits for this wave's 16 rows
    f32x4 c4 = {0.f, 0.f, 0.f, 0.f};
    int rowl = wv*16 + lm;
    int f1 = (rowl ^ (rowl >> 3)) & 7;
    #pragma unroll
    for(int k = 0; k < 8; k++){
      int cc = (k*4 + lg) ^ f1;
      bf16x8 a = *(const bf16x8*)(&xt[rowl*256 + cc*8]);
      c4 = mfma16(a, qb[k], c4);
    }
    // softmax over slots
    float pv[4];
    #pragma unroll
    for(int reg = 0; reg < 4; reg++){
      float v = (lm < 8) ? c4[reg] : -1e30f;
      float mx = v;
      #pragma unroll
      for(int m = 1; m < 16; m <<= 1) mx = fmaxf(mx, __shfl_xor(mx, m));
      float e = __expf(v - mx);
      float s = e;
      #pragma unroll
      for(int m = 1; m < 16; m <<= 1) s += __shfl_xor(s, m);
      float p = (lm < 8) ? (e/s + 1e-8f) : 0.0f;
      dacc += p;
      pv[reg] = p;
    }
    int rbase = wv*16 + lg*4;
    unsigned int p01 = (unsigned)f2bf(pv[0]) | ((unsigned)f2bf(pv[1]) << 16);
    unsigned int p23 = (unsigned)f2bf(pv[2]) | ((unsigned)f2bf(pv[3]) << 16);
    *(unsigned int*)(&pt[lm*72 + rbase])     = p01;
    *(unsigned int*)(&pt[lm*72 + rbase + 2]) = p23;
    __syncthreads();

    // phase 2: U[s, e-slice] += P^T @ X
    #pragma unroll
    for(int ks = 0; ks < 2; ks++){
      bf16x8 a = *(const bf16x8*)(&pt[lm*72 + ks*32 + lg*8]);
      int rb = ks*32 + lg*8;
      #pragma unroll
      for(int nt = 0; nt < 4; nt++){
        int e = wv*64 + nt*16 + lm;
        bf16x8 bfr;
        #pragma unroll
        for(int j = 0; j < 8; j++){
          int row2 = rb + j;
          int f2 = (row2 ^ (row2 >> 3)) & 7;
          int cidx = (e >> 3) ^ f2;
          unsigned short tv = xt[row2*256 + cidx*8 + (e & 7)];
          bfr[j] = __builtin_bit_cast(bf16_t, tv);
        }
        uacc[nt] = mfma16(a, bfr, uacc[nt]);
      }
    }
  }

  // epilogue
  dacc += __shfl_xor(dacc, 16);
  dacc += __shfl_xor(dacc, 32);
  if(l < 8) atomicAdd(&den[b*CS + l], dacc);
  if(lg < 2){
    #pragma unroll
    for(int nt = 0; nt < 4; nt++){
      #pragma unroll
      for(int reg = 0; reg < 4; reg++){
        int s = lg*4 + reg;
        atomicAdd(&U[((size_t)b*CS + s)*CD + wv*64 + nt*16 + lm], uacc[nt][reg]);
      }
    }
  }
}

// ---------------- MFMA bf16 GEMM: C[M x N] = A(fp32)[M x K] @ Bt(bf16)[N x K]^T ----------------
// 64x64 tile per block, 4 waves; A converted fp32->bf16 during LDS staging.
// EPI 0: plain store. EPI 1: relu(acc + bias[n]). EPI 2: acc + bias[n] + res[m][n].
template<int EPI>
__global__ __launch_bounds__(256) void k_gemm_bf(
    const float* __restrict__ A, const unsigned short* __restrict__ Bt,
    float* __restrict__ C, int K, int N, int ntn,
    const float* __restrict__ bias, const float* __restrict__ res,
    const float* __restrict__ A2, const unsigned short* __restrict__ Bt2,
    float* __restrict__ C2){
  __shared__ unsigned short As[64*72];   // stride 72 bf16: b128 reads at 8-dword/bank min
  __shared__ unsigned short Bs[64*72];
  if(blockIdx.y == 1){ A = A2; Bt = Bt2; C = C2; }
  int bm = blockIdx.x / ntn, bn = blockIdx.x % ntn;
  int m0 = bm*64, n0 = bn*64;
  int tid = threadIdx.x;
  int wv = tid >> 6, l = tid & 63, lm = l & 15, lg = l >> 4;
  int sr = tid >> 2, sc = (tid & 3)*8;   // staging: row 0..63, col-chunk of 8

  f32x4 acc[4];
  #pragma unroll
  for(int nt = 0; nt < 4; nt++){ f32x4 z = {0.f,0.f,0.f,0.f}; acc[nt] = z; }

  for(int k0 = 0; k0 < K; k0 += 32){
    __syncthreads();
    {
      const float* src = A + (size_t)(m0 + sr)*K + k0 + sc;
      float4 a0 = *(const float4*)(src);
      float4 a1 = *(const float4*)(src + 4);
      uint4 pk;
      pk.x = (unsigned)f2bf(a0.x) | ((unsigned)f2bf(a0.y) << 16);
      pk.y = (unsigned)f2bf(a0.z) | ((unsigned)f2bf(a0.w) << 16);
      pk.z = (unsigned)f2bf(a1.x) | ((unsigned)f2bf(a1.y) << 16);
      pk.w = (unsigned)f2bf(a1.z) | ((unsigned)f2bf(a1.w) << 16);
      *(uint4*)(&As[sr*72 + sc]) = pk;
      uint4 bv = *(const uint4*)(Bt + (size_t)(n0 + sr)*K + k0 + sc);
      *(uint4*)(&Bs[sr*72 + sc]) = bv;
    }
    __syncthreads();
    bf16x8 af = *(const bf16x8*)(&As[(wv*16 + lm)*72 + lg*8]);
    #pragma unroll
    for(int nt = 0; nt < 4; nt++){
      bf16x8 bf = *(const bf16x8*)(&Bs[(nt*16 + lm)*72 + lg*8]);
      acc[nt] = mfma16(af, bf, acc[nt]);
    }
  }

  #pragma unroll
  for(int nt = 0; nt < 4; nt++){
    int n = n0 + nt*16 + lm;
    float bi = (EPI != 0) ? bias[n] : 0.0f;
    #pragma unroll
    for(int reg = 0; reg < 4; reg++){
      int m = m0 + wv*16 + lg*4 + reg;
      float vv = acc[nt][reg];
      if(EPI == 1) vv = fmaxf(vv + bi, 0.0f);
      else if(EPI == 2) vv = vv + bi + res[(size_t)m*N + n];
      C[(size_t)m*N + n] = vv;
    }
  }
}

// ---------------- GRU gate activations + LN(mlp) prep; wave per row ----------------
__global__ __launch_bounds__(256) void k_act(const float* __restrict__ gi,
    const float* __restrict__ gh, const float* __restrict__ den,
    const float* __restrict__ slots, const float* __restrict__ bih,
    const float* __restrict__ bhh, const float* __restrict__ lw,
    const float* __restrict__ lb, float* __restrict__ hp, float* __restrict__ lnh){
  int wv = threadIdx.x >> 6, l = threadIdx.x & 63;
  int row = blockIdx.x*4 + wv;
  const float* gir = gi + (size_t)row*768;
  const float* ghr = gh + (size_t)row*768;
  float invd = 1.0f / den[row];
  float4 air = *(const float4*)(gir + 4*l);
  float4 aiz = *(const float4*)(gir + 256 + 4*l);
  float4 ain = *(const float4*)(gir + 512 + 4*l);
  float4 ahr = *(const float4*)(ghr + 4*l);
  float4 ahz = *(const float4*)(ghr + 256 + 4*l);
  float4 ahn = *(const float4*)(ghr + 512 + 4*l);
  float4 br = *(const float4*)(bih + 4*l);
  float4 bz = *(const float4*)(bih + 256 + 4*l);
  float4 bn = *(const float4*)(bih + 512 + 4*l);
  float4 cr = *(const float4*)(bhh + 4*l);
  float4 cz = *(const float4*)(bhh + 256 + 4*l);
  float4 cn = *(const float4*)(bhh + 512 + 4*l);
  float4 hc = *(const float4*)(slots + (size_t)row*256 + 4*l);
  float4 h;
  #pragma unroll
  for(int i = 0; i < 4; i++){
    float gr = (&air.x)[i]*invd + (&br.x)[i] + (&ahr.x)[i] + (&cr.x)[i];
    float gz = (&aiz.x)[i]*invd + (&bz.x)[i] + (&ahz.x)[i] + (&cz.x)[i];
    float gn = (&ain.x)[i]*invd + (&bn.x)[i];
    float hn = (&ahn.x)[i] + (&cn.x)[i];
    float r = 1.0f/(1.0f + __expf(-gr));
    float z = 1.0f/(1.0f + __expf(-gz));
    float n = tanhf(gn + r*hn);
    (&h.x)[i] = (1.0f - z)*n + z*(&hc.x)[i];
  }
  *(float4*)(hp + (size_t)row*256 + 4*l) = h;
  float s1 = h.x + h.y + h.z + h.w;
  float s2 = h.x*h.x + h.y*h.y + h.z*h.z + h.w*h.w;
  #pragma unroll
  for(int m = 1; m < 64; m <<= 1){ s1 += __shfl_xor(s1, m); s2 += __shfl_xor(s2, m); }
  float mean = s1 * (1.0f/CD);
  float var  = fmaxf(s2 * (1.0f/CD) - mean*mean, 0.0f);
  float rstd = rsqrtf(var + 1e-5f);
  float4 w4 = *(const float4*)(lw + 4*l);
  float4 b4 = *(const float4*)(lb + 4*l);
  float4 o;
  o.x = (h.x - mean)*rstd*w4.x + b4.x;
  o.y = (h.y - mean)*rstd*w4.y + b4.y;
  o.z = (h.z - mean)*rstd*w4.z + b4.z;
  o.w = (h.w - mean)*rstd*w4.w + b4.w;
  *(float4*)(lnh + (size_t)row*256 + 4*l) = o;
}

extern "C" void kernel_launch(void* const* d_in, const int* in_sizes, int n_in,
                              void* d_out, int out_size, void* d_ws, size_t ws_size,
                              hipStream_t stream){
  const float* inputs = (const float*)d_in[0];
  const float* noise  = (const float*)d_in[1];
  const float* ln_in_w = (const float*)d_in[2];
  const float* ln_in_b = (const float*)d_in[3];
  const float* ln_sl_w = (const float*)d_in[4];
  const float* ln_sl_b = (const float*)d_in[5];
  const float* ln_ml_w = (const float*)d_in[6];
  const float* ln_ml_b = (const float*)d_in[7];
  const float* mu   = (const float*)d_in[8];
  const float* lsig = (const float*)d_in[9];
  const float* Wq  = (const float*)d_in[10];
  const float* Wk  = (const float*)d_in[11];
  const float* Wv  = (const float*)d_in[12];
  const float* wih = (const float*)d_in[13];
  const float* whh = (const float*)d_in[14];
  const float* bih = (const float*)d_in[15];
  const float* bhh = (const float*)d_in[16];
  const float* w1  = (const float*)d_in[17];
  const float* b1  = (const float*)d_in[18];
  const float* w2  = (const float*)d_in[19];
  const float* b2  = (const float*)d_in[20];

  char* ws = (char*)d_ws;
  size_t off = 0;
  unsigned short* x = (unsigned short*)(ws + off); off += (size_t)CB*CN*CD*2;
  float* slots = (float*)(ws + off); off += (size_t)CB*CS*CD*4;
  float* hp    = (float*)(ws + off); off += (size_t)CB*CS*CD*4;
  float* U     = (float*)(ws + off); off += (size_t)CB*CS*CD*4;
  float* den   = (float*)(ws + off); off += (size_t)CB*CS*4;
  unsigned short* qt     = (unsigned short*)(ws + off); off += (size_t)CB*16*CD*2;
  unsigned short* M1T    = (unsigned short*)(ws + off); off += (size_t)CD*CD*2;
  unsigned short* Mih_bf = (unsigned short*)(ws + off); off += (size_t)768*CD*2;
  unsigned short* Whh_bf = (unsigned short*)(ws + off); off += (size_t)768*CD*2;
  unsigned short* w1_bf  = (unsigned short*)(ws + off); off += (size_t)CH*CD*2;
  unsigned short* w2_bf  = (unsigned short*)(ws + off); off += (size_t)CD*CH*2;
  float* gi   = (float*)(ws + off); off += (size_t)512*768*4;
  float* gh   = (float*)(ws + off); off += (size_t)512*768*4;
  float* lnh  = (float*)(ws + off); off += (size_t)512*256*4;
  float* h1   = (float*)(ws + off); off += (size_t)512*512*4;

  k_pre<<<7424, 256, 0, stream>>>(inputs, ln_in_w, ln_in_b, x,
                                  Wq, Wk, wih, Wv, whh, w1, w2, noise, mu, lsig,
                                  M1T, Mih_bf, Whh_bf, w1_bf, w2_bf, slots);

  for(int it = 0; it < 3; it++){
    k_qt<<<64, 256, 0, stream>>>(slots, ln_sl_w, ln_sl_b, M1T, qt, U, den);
    k_attn<<<1024, 256, 0, stream>>>(x, qt, U, den);
    // gates: gi = U @ Mih^T [512x768], gh = slots @ Whh^T [512x768]   (K=256, N=768)
    k_gemm_bf<0><<<dim3(96, 2), 256, 0, stream>>>(
        U, Mih_bf, gi, 256, 768, 12, nullptr, nullptr,
        slots, Whh_bf, gh);
    k_act<<<128, 256, 0, stream>>>(gi, gh, den, slots, bih, bhh, ln_ml_w, ln_ml_b, hp, lnh);
    // h1 = relu(lnh @ w1^T + b1)  [512x512]  (K=256, N=512)
    k_gemm_bf<1><<<dim3(64, 1), 256, 0, stream>>>(
        lnh, w1_bf, h1, 256, 512, 8, b1, nullptr,
        nullptr, nullptr, nullptr);
    // slots_next = h1 @ w2^T + b2 + hp  [512x256]  (K=512, N=256); last iter -> d_out
    float* cdst = (it == 2) ? (float*)d_out : slots;
    k_gemm_bf<2><<<dim3(32, 1), 256, 0, stream>>>(
        h1, w2_bf, cdst, 512, 256, 4, b2, hp,
        nullptr, nullptr, nullptr);
  }
}